// Round 1
// baseline (87.416 us; speedup 1.0000x reference)
//
#include <hip/hip_runtime.h>
#include <math.h>
#include <cfloat>

#define BLOCK 256

// For each query point q (one thread), scan a chunk of the reference cloud
// staged in LDS as float4(-2x, -2y, -2z, x^2+y^2+z^2) and track
// min_e = min_n (||r_n||^2 - 2 q.r_n)  (equals d^2 - ||q||^2, monotone in d^2)
// plus argmin. Writes (e_min, idx) partial per (b, q, chunk).
__global__ void chamfer_min_kernel(const float* __restrict__ pcq,
                                   const float* __restrict__ pcr,
                                   float2* __restrict__ part,
                                   int NQ, int NR, int CS, int RC) {
    extern __shared__ float4 lds[];
    const int b = blockIdx.y;
    const int chunk = blockIdx.z;
    const int tid = threadIdx.x;
    const int n0 = chunk * CS;

    // Stage reference chunk into LDS (coalesced global reads).
    const float* rbase = pcr + (size_t)b * 3 * NR;
    for (int i = tid; i < CS; i += BLOCK) {
        float rx = rbase[n0 + i];
        float ry = rbase[NR + n0 + i];
        float rz = rbase[2 * NR + n0 + i];
        lds[i] = make_float4(-2.0f * rx, -2.0f * ry, -2.0f * rz,
                             rx * rx + ry * ry + rz * rz);
    }

    // This thread's query point (coalesced).
    const int q = blockIdx.x * BLOCK + tid;
    const float* qbase = pcq + (size_t)b * 3 * NQ;
    const float qx = qbase[q];
    const float qy = qbase[NQ + q];
    const float qz = qbase[2 * NQ + q];

    __syncthreads();

    float emin = FLT_MAX;
    int imin = 0;
#pragma unroll 4
    for (int i = 0; i < CS; ++i) {
        const float4 r = lds[i];   // uniform address across lanes -> broadcast
        float e = fmaf(qx, r.x, r.w);
        e = fmaf(qy, r.y, e);
        e = fmaf(qz, r.z, e);
        if (e < emin) { emin = e; imin = i; }   // strict < : first index wins
    }
    part[((size_t)b * NQ + q) * RC + chunk] =
        make_float2(emin, (float)(n0 + imin));
}

// Fold RC partials per query, finish distance, gather sigmas, block-reduce,
// one atomicAdd per block into the scalar output.
__global__ void chamfer_reduce_kernel(const float* __restrict__ pcq,
                                      const float* __restrict__ sigq,
                                      const float* __restrict__ sigr,
                                      const float2* __restrict__ part,
                                      float* __restrict__ out,
                                      int NQ, int NR, int RC, float scale) {
    __shared__ float red[BLOCK];
    const int t = blockIdx.x * BLOCK + threadIdx.x;   // t = b*NQ + q
    const int b = t / NQ;
    const int q = t - b * NQ;

    float emin = FLT_MAX;
    float fidx = 0.0f;
    const float2* p = part + (size_t)t * RC;
    for (int c = 0; c < RC; ++c) {     // ascending chunk order keeps first idx
        const float2 pc = p[c];
        if (pc.x < emin) { emin = pc.x; fidx = pc.y; }
    }

    const float* qbase = pcq + (size_t)b * 3 * NQ;
    const float qx = qbase[q];
    const float qy = qbase[NQ + q];
    const float qz = qbase[2 * NQ + q];
    const float d2 = fmaxf(emin + (qx * qx + qy * qy + qz * qz), 0.0f);
    const float dist = sqrtf(d2);

    const int idx = (int)fidx;
    const float s = 0.5f * (sigq[t] + sigr[(size_t)b * NR + idx]);
    red[threadIdx.x] = dist * s * scale;
    __syncthreads();

    for (int w = BLOCK / 2; w > 0; w >>= 1) {
        if (threadIdx.x < w) red[threadIdx.x] += red[threadIdx.x + w];
        __syncthreads();
    }
    if (threadIdx.x == 0) atomicAdd(out, red[0]);
}

extern "C" void kernel_launch(void* const* d_in, const int* in_sizes, int n_in,
                              void* d_out, int out_size, void* d_ws, size_t ws_size,
                              hipStream_t stream) {
    const float* pc_src  = (const float*)d_in[0];   // [B,3,M]
    const float* pc_dst  = (const float*)d_in[1];   // [B,3,N]
    const float* sig_src = (const float*)d_in[2];   // [B,M]
    const float* sig_dst = (const float*)d_in[3];   // [B,N]
    float* out = (float*)d_out;

    const int B = 8;
    const int M = in_sizes[2] / B;   // 4096
    const int N = in_sizes[3] / B;   // 4096
    const int NMAX = (M > N) ? M : N;

    // Pick reference-chunk count RC fitting the workspace (RC=4 -> 1 MiB).
    int RC = 4;
    while (RC > 1 && (size_t)B * NMAX * RC * sizeof(float2) > ws_size) RC >>= 1;

    float2* part = (float2*)d_ws;

    hipMemsetAsync(d_out, 0, sizeof(float), stream);

    // forward: query = src, reference = dst
    {
        const int CS = N / RC;
        dim3 grid(M / BLOCK, B, RC);
        chamfer_min_kernel<<<grid, BLOCK, CS * sizeof(float4), stream>>>(
            pc_src, pc_dst, part, M, N, CS, RC);
        dim3 rgrid((B * M) / BLOCK);
        chamfer_reduce_kernel<<<rgrid, BLOCK, 0, stream>>>(
            pc_src, sig_src, sig_dst, part, out, M, N, RC, 1.0f / (float)(B * M));
    }
    // backward: query = dst, reference = src
    {
        const int CS = M / RC;
        dim3 grid(N / BLOCK, B, RC);
        chamfer_min_kernel<<<grid, BLOCK, CS * sizeof(float4), stream>>>(
            pc_dst, pc_src, part, N, M, CS, RC);
        dim3 rgrid((B * N) / BLOCK);
        chamfer_reduce_kernel<<<rgrid, BLOCK, 0, stream>>>(
            pc_dst, sig_dst, sig_src, part, out, N, M, RC, 1.0f / (float)(B * N));
    }
}

// Round 2
// 70.545 us; speedup vs baseline: 1.2391x; 1.2391x over previous
//
#include <hip/hip_runtime.h>
#include <math.h>
#include <cfloat>

#define BLOCK 256
#define QPT 4   // query points per thread: one broadcast LDS read feeds 4x work

// For each query point q, scan a chunk of the reference cloud staged in LDS as
// float4(-2x, -2y, -2z, x^2+y^2+z^2) and track
// min_e = min_n (||r_n||^2 - 2 q.r_n)  (= d^2 - ||q||^2, monotone in d^2)
// plus argmin. Each thread handles QPT queries so the ~12cy ds_read_b128
// broadcast (the binding pipe at QPT=1, measured 11.9 cy/iter in R1) is
// amortized over 4x the pairs. Writes (e_min, idx) partial per (b, q, chunk).
__global__ void chamfer_min_kernel(const float* __restrict__ pcq,
                                   const float* __restrict__ pcr,
                                   float2* __restrict__ part,
                                   int NQ, int NR, int CS, int RC) {
    extern __shared__ float4 lds[];
    const int b = blockIdx.y;
    const int chunk = blockIdx.z;
    const int tid = threadIdx.x;
    const int n0 = chunk * CS;

    // Stage reference chunk into LDS (coalesced global reads).
    const float* rbase = pcr + (size_t)b * 3 * NR;
    for (int i = tid; i < CS; i += BLOCK) {
        float rx = rbase[n0 + i];
        float ry = rbase[NR + n0 + i];
        float rz = rbase[2 * NR + n0 + i];
        lds[i] = make_float4(-2.0f * rx, -2.0f * ry, -2.0f * rz,
                             rx * rx + ry * ry + rz * rz);
    }

    // This thread's QPT query points (coalesced per sub-block).
    const int q0 = blockIdx.x * (BLOCK * QPT) + tid;
    const float* qbase = pcq + (size_t)b * 3 * NQ;
    float qx[QPT], qy[QPT], qz[QPT], emin[QPT];
    int imin[QPT];
#pragma unroll
    for (int j = 0; j < QPT; ++j) {
        const int q = q0 + j * BLOCK;
        qx[j] = qbase[q];
        qy[j] = qbase[NQ + q];
        qz[j] = qbase[2 * NQ + q];
        emin[j] = FLT_MAX;
        imin[j] = 0;
    }

    __syncthreads();

#pragma unroll 2
    for (int i = 0; i < CS; ++i) {
        const float4 r = lds[i];   // uniform address across lanes -> broadcast
#pragma unroll
        for (int j = 0; j < QPT; ++j) {
            float e = fmaf(qx[j], r.x, r.w);
            e = fmaf(qy[j], r.y, e);
            e = fmaf(qz[j], r.z, e);
            if (e < emin[j]) { emin[j] = e; imin[j] = i; }  // strict <: first idx wins
        }
    }

#pragma unroll
    for (int j = 0; j < QPT; ++j) {
        const int q = q0 + j * BLOCK;
        part[((size_t)b * NQ + q) * RC + chunk] =
            make_float2(emin[j], (float)(n0 + imin[j]));
    }
}

// Fold RC partials per query, finish distance, gather sigmas, block-reduce,
// one atomicAdd per block into the scalar output.
__global__ void chamfer_reduce_kernel(const float* __restrict__ pcq,
                                      const float* __restrict__ sigq,
                                      const float* __restrict__ sigr,
                                      const float2* __restrict__ part,
                                      float* __restrict__ out,
                                      int NQ, int NR, int RC, float scale) {
    __shared__ float red[BLOCK];
    const int t = blockIdx.x * BLOCK + threadIdx.x;   // t = b*NQ + q
    const int b = t / NQ;
    const int q = t - b * NQ;

    float emin = FLT_MAX;
    float fidx = 0.0f;
    const float2* p = part + (size_t)t * RC;
    for (int c = 0; c < RC; ++c) {     // ascending chunk order keeps first idx
        const float2 pc = p[c];
        if (pc.x < emin) { emin = pc.x; fidx = pc.y; }
    }

    const float* qbase = pcq + (size_t)b * 3 * NQ;
    const float qx = qbase[q];
    const float qy = qbase[NQ + q];
    const float qz = qbase[2 * NQ + q];
    const float d2 = fmaxf(emin + (qx * qx + qy * qy + qz * qz), 0.0f);
    const float dist = sqrtf(d2);

    const int idx = (int)fidx;
    const float s = 0.5f * (sigq[t] + sigr[(size_t)b * NR + idx]);
    red[threadIdx.x] = dist * s * scale;
    __syncthreads();

    for (int w = BLOCK / 2; w > 0; w >>= 1) {
        if (threadIdx.x < w) red[threadIdx.x] += red[threadIdx.x + w];
        __syncthreads();
    }
    if (threadIdx.x == 0) atomicAdd(out, red[0]);
}

extern "C" void kernel_launch(void* const* d_in, const int* in_sizes, int n_in,
                              void* d_out, int out_size, void* d_ws, size_t ws_size,
                              hipStream_t stream) {
    const float* pc_src  = (const float*)d_in[0];   // [B,3,M]
    const float* pc_dst  = (const float*)d_in[1];   // [B,3,N]
    const float* sig_src = (const float*)d_in[2];   // [B,M]
    const float* sig_dst = (const float*)d_in[3];   // [B,N]
    float* out = (float*)d_out;

    const int B = 8;
    const int M = in_sizes[2] / B;   // 4096
    const int N = in_sizes[3] / B;   // 4096
    const int NMAX = (M > N) ? M : N;

    // Pick reference-chunk count RC fitting the workspace (RC=16 -> 4 MiB).
    int RC = 16;
    while (RC > 1 && (size_t)B * NMAX * RC * sizeof(float2) > ws_size) RC >>= 1;

    float2* part = (float2*)d_ws;

    hipMemsetAsync(d_out, 0, sizeof(float), stream);

    // forward: query = src, reference = dst
    {
        const int CS = N / RC;
        dim3 grid(M / (BLOCK * QPT), B, RC);
        chamfer_min_kernel<<<grid, BLOCK, CS * sizeof(float4), stream>>>(
            pc_src, pc_dst, part, M, N, CS, RC);
        dim3 rgrid((B * M) / BLOCK);
        chamfer_reduce_kernel<<<rgrid, BLOCK, 0, stream>>>(
            pc_src, sig_src, sig_dst, part, out, M, N, RC, 1.0f / (float)(B * M));
    }
    // backward: query = dst, reference = src
    {
        const int CS = M / RC;
        dim3 grid(N / (BLOCK * QPT), B, RC);
        chamfer_min_kernel<<<grid, BLOCK, CS * sizeof(float4), stream>>>(
            pc_dst, pc_src, part, N, M, CS, RC);
        dim3 rgrid((B * N) / BLOCK);
        chamfer_reduce_kernel<<<rgrid, BLOCK, 0, stream>>>(
            pc_dst, sig_dst, sig_src, part, out, N, M, RC, 1.0f / (float)(B * N));
    }
}

// Round 3
// 60.377 us; speedup vs baseline: 1.4478x; 1.1684x over previous
//
#include <hip/hip_runtime.h>
#include <math.h>
#include <cfloat>

#define BLOCK 256
#define QPT 4   // query points per thread: one broadcast LDS read feeds 4x work

// For each query point q, scan a chunk of the reference cloud staged in LDS as
// float4(-2x, -2y, -2z, x^2+y^2+z^2) and track
// min_e = min_n (||r_n||^2 - 2 q.r_n)  (= d^2 - ||q||^2, monotone in d^2)
// plus argmin. QPT queries/thread amortize the broadcast ds_read_b128.
// RC=32 chunks -> 1024 blocks = 4/CU (16 waves/CU) to hide LDS latency,
// which R2's post-mortem identified as the real limiter (2 waves/SIMD could
// not cover ~120cy ds_read latency + the serial emin cmp/cndmask chain).
// Partials are chunk-major: part[(chunk*B + b)*NQ + q] so both the write here
// and the fold in the reduce kernel are coalesced in q.
__global__ void chamfer_min_kernel(const float* __restrict__ pcq,
                                   const float* __restrict__ pcr,
                                   float2* __restrict__ part,
                                   int NQ, int NR, int CS, int B,
                                   float* out_zero) {
    extern __shared__ float4 lds[];
    const int b = blockIdx.y;
    const int chunk = blockIdx.z;
    const int tid = threadIdx.x;
    const int n0 = chunk * CS;

    if (out_zero && blockIdx.x == 0 && b == 0 && chunk == 0 && tid == 0)
        *out_zero = 0.0f;   // reduce kernel runs strictly later in-stream

    // Stage reference chunk into LDS (coalesced global reads).
    const float* rbase = pcr + (size_t)b * 3 * NR;
    for (int i = tid; i < CS; i += BLOCK) {
        float rx = rbase[n0 + i];
        float ry = rbase[NR + n0 + i];
        float rz = rbase[2 * NR + n0 + i];
        lds[i] = make_float4(-2.0f * rx, -2.0f * ry, -2.0f * rz,
                             rx * rx + ry * ry + rz * rz);
    }

    // This thread's QPT query points (coalesced per sub-block).
    const int q0 = blockIdx.x * (BLOCK * QPT) + tid;
    const float* qbase = pcq + (size_t)b * 3 * NQ;
    float qx[QPT], qy[QPT], qz[QPT], emin[QPT];
    int imin[QPT];
#pragma unroll
    for (int j = 0; j < QPT; ++j) {
        const int q = q0 + j * BLOCK;
        qx[j] = qbase[q];
        qy[j] = qbase[NQ + q];
        qz[j] = qbase[2 * NQ + q];
        emin[j] = FLT_MAX;
        imin[j] = 0;
    }

    __syncthreads();

#pragma unroll 4
    for (int i = 0; i < CS; ++i) {
        const float4 r = lds[i];   // uniform address across lanes -> broadcast
#pragma unroll
        for (int j = 0; j < QPT; ++j) {
            float e = fmaf(qx[j], r.x, r.w);
            e = fmaf(qy[j], r.y, e);
            e = fmaf(qz[j], r.z, e);
            if (e < emin[j]) { emin[j] = e; imin[j] = i; }  // strict <: first idx wins
        }
    }

#pragma unroll
    for (int j = 0; j < QPT; ++j) {
        const int q = q0 + j * BLOCK;
        part[((size_t)chunk * B + b) * NQ + q] =
            make_float2(emin[j], (float)(n0 + imin[j]));
    }
}

// One kernel for BOTH directions: thread t < B*M handles src->dst query t,
// else dst->src query t - B*M. Folds RC chunk partials (coalesced reads),
// finishes the distance, gathers sigmas, block-reduces, one atomicAdd/block.
__global__ void chamfer_reduce_kernel(const float* __restrict__ pc_src,
                                      const float* __restrict__ pc_dst,
                                      const float* __restrict__ sig_src,
                                      const float* __restrict__ sig_dst,
                                      const float2* __restrict__ part0,
                                      const float2* __restrict__ part1,
                                      float* __restrict__ out,
                                      int M, int N, int B, int RC) {
    __shared__ float red[BLOCK];
    const int TT = blockIdx.x * BLOCK + threadIdx.x;
    const int dir = (TT >= B * M);            // uniform per block (B*M % 256 == 0)
    const int t = dir ? TT - B * M : TT;      // t = b*NQ + q

    const int NQ = dir ? N : M;
    const int NR = dir ? M : N;
    const float* pcq  = dir ? pc_dst : pc_src;
    const float* sigq = dir ? sig_dst : sig_src;
    const float* sigr = dir ? sig_src : sig_dst;
    const float2* part = dir ? part1 : part0;
    const float scale = 1.0f / (float)(B * NQ);

    const int b = t / NQ;
    const int q = t - b * NQ;

    float emin = FLT_MAX;
    float fidx = 0.0f;
    for (int c = 0; c < RC; ++c) {   // ascending chunk order keeps first idx
        const float2 pc = part[((size_t)c * B + b) * NQ + q];
        if (pc.x < emin) { emin = pc.x; fidx = pc.y; }
    }

    const float* qbase = pcq + (size_t)b * 3 * NQ;
    const float qx = qbase[q];
    const float qy = qbase[NQ + q];
    const float qz = qbase[2 * NQ + q];
    const float d2 = fmaxf(emin + (qx * qx + qy * qy + qz * qz), 0.0f);
    const float dist = sqrtf(d2);

    const int idx = (int)fidx;
    const float s = 0.5f * (sigq[t] + sigr[(size_t)b * NR + idx]);
    red[threadIdx.x] = dist * s * scale;
    __syncthreads();

    for (int w = BLOCK / 2; w > 0; w >>= 1) {
        if (threadIdx.x < w) red[threadIdx.x] += red[threadIdx.x + w];
        __syncthreads();
    }
    if (threadIdx.x == 0) atomicAdd(out, red[0]);
}

extern "C" void kernel_launch(void* const* d_in, const int* in_sizes, int n_in,
                              void* d_out, int out_size, void* d_ws, size_t ws_size,
                              hipStream_t stream) {
    const float* pc_src  = (const float*)d_in[0];   // [B,3,M]
    const float* pc_dst  = (const float*)d_in[1];   // [B,3,N]
    const float* sig_src = (const float*)d_in[2];   // [B,M]
    const float* sig_dst = (const float*)d_in[3];   // [B,N]
    float* out = (float*)d_out;

    const int B = 8;
    const int M = in_sizes[2] / B;   // 4096
    const int N = in_sizes[3] / B;   // 4096
    const int NMAX = (M > N) ? M : N;

    // RC=32 -> 1024 blocks/direction (4 blocks/CU). Shrink if ws too small.
    int RC = 32;
    while (RC > 1 && 2 * (size_t)B * NMAX * RC * sizeof(float2) > ws_size) RC >>= 1;

    float2* part0 = (float2*)d_ws;                      // src->dst partials
    float2* part1 = part0 + (size_t)RC * B * M;         // dst->src partials

    // forward: query = src, reference = dst (also zeroes d_out)
    {
        const int CS = N / RC;
        dim3 grid(M / (BLOCK * QPT), B, RC);
        chamfer_min_kernel<<<grid, BLOCK, CS * sizeof(float4), stream>>>(
            pc_src, pc_dst, part0, M, N, CS, B, out);
    }
    // backward: query = dst, reference = src
    {
        const int CS = M / RC;
        dim3 grid(N / (BLOCK * QPT), B, RC);
        chamfer_min_kernel<<<grid, BLOCK, CS * sizeof(float4), stream>>>(
            pc_dst, pc_src, part1, N, M, CS, B, nullptr);
    }
    // fused reduce over both directions
    {
        dim3 rgrid((B * (M + N)) / BLOCK);
        chamfer_reduce_kernel<<<rgrid, BLOCK, 0, stream>>>(
            pc_src, pc_dst, sig_src, sig_dst, part0, part1, out, M, N, B, RC);
    }
}